// Round 14
// baseline (79.625 us; speedup 1.0000x reference)
//
#include <hip/hip_runtime.h>
#include <hip/hip_bf16.h>

#define Bn 64
#define Tn 512
#define Dn 512
#define Hn 128
#define BT (Bn*Tn)

typedef unsigned short u16;
typedef unsigned long long u64;
typedef __attribute__((ext_vector_type(8))) short bf16x8;
typedef __attribute__((ext_vector_type(4))) float f32x4;

__device__ __forceinline__ u16 f2bf(float f) {
  union { float f; unsigned u; } v; v.f = f;
  unsigned r = (v.u + 0x7FFFu + ((v.u >> 16) & 1u)) >> 16;
  return (u16)r;
}

__device__ __forceinline__ bf16x8 pack8(float4 a, float4 b) {
  bf16x8 o;
  o[0] = (short)f2bf(a.x); o[1] = (short)f2bf(a.y);
  o[2] = (short)f2bf(a.z); o[3] = (short)f2bf(a.w);
  o[4] = (short)f2bf(b.x); o[5] = (short)f2bf(b.y);
  o[6] = (short)f2bf(b.z); o[7] = (short)f2bf(b.w);
  return o;
}

// async global->LDS, 16B/lane; LDS dest = wave-uniform base (+lane*16 by HW)
__device__ __forceinline__ void gload16(const void* g, void* lds) {
  __builtin_amdgcn_global_load_lds(
      (const __attribute__((address_space(1))) unsigned int*)g,
      (__attribute__((address_space(3))) unsigned int*)lds, 16, 0, 0);
}

// ---------- prep: all three W -> bf16 (one launch) ----------
__global__ __launch_bounds__(256) void conv_w3(const float4* __restrict__ Wk,
                                               const float4* __restrict__ Wq,
                                               const float4* __restrict__ Wv,
                                               ushort4* __restrict__ out) {
  int idx = blockIdx.x * 256 + threadIdx.x;        // 3 * 16384
  int which = idx >> 14, j = idx & 16383;
  const float4* src = (which == 0) ? Wk : (which == 1) ? Wq : Wv;
  float4 v = src[j];
  ushort4 o; o.x = f2bf(v.x); o.y = f2bf(v.y); o.z = f2bf(v.z); o.w = f2bf(v.w);
  out[idx] = o;
}

// ---------- prep: dag transpose + bf16 + mask bits (fused) ----------
__global__ __launch_bounds__(256) void dag_tr(const float* __restrict__ dag,
                                              u16* __restrict__ dagT,
                                              u64* __restrict__ bits) {
  __shared__ float s[64][65];
  int bx = blockIdx.x & 7, by = blockIdx.x >> 3;
  int r0 = by * 64, c0 = bx * 64;
  int t = threadIdx.x;
  int c4 = t & 15, rr = t >> 4;
#pragma unroll
  for (int q = 0; q < 4; ++q) {
    int r = rr + q * 16;
    float4 v = *(const float4*)&dag[(size_t)(r0 + r) * Tn + c0 + c4 * 4];
    s[c4 * 4 + 0][r] = v.x; s[c4 * 4 + 1][r] = v.y;
    s[c4 * 4 + 2][r] = v.z; s[c4 * 4 + 3][r] = v.w;
  }
  __syncthreads();
#pragma unroll
  for (int q = 0; q < 4; ++q) {
    int il = rr + q * 16;
    ushort4 o;
    u64 b4 = 0;
#pragma unroll
    for (int r = 0; r < 4; ++r) {
      float v = s[il][c4 * 4 + r];
      ((u16*)&o)[r] = f2bf(v);
      b4 |= (u64)(v != 0.f) << (c4 * 4 + r);
    }
    *(ushort4*)&dagT[(size_t)(c0 + il) * Tn + r0 + c4 * 4] = o;
    b4 |= __shfl_xor(b4, 1, 64);
    b4 |= __shfl_xor(b4, 2, 64);
    b4 |= __shfl_xor(b4, 4, 64);
    b4 |= __shfl_xor(b4, 8, 64);
    if (c4 == 0) bits[(size_t)(c0 + il) * 8 + (r0 >> 6)] = b4;
  }
}

// ---------- stage 1: K,Q,V = swish(X W^T + b); BM=64, 2 blocks/CU, T14 X-prefetch ----------
// grid BT/64 = 512, 256 threads (4 waves; wave w owns h-cols w*32..w*32+31).
__global__ __launch_bounds__(256, 2) void qkv3(
    const float* __restrict__ X, const u16* __restrict__ Wcat,
    const float* __restrict__ bk, const float* __restrict__ bq,
    const float* __restrict__ bv,
    u16* __restrict__ Kb, u16* __restrict__ QT, u16* __restrict__ VT) {
  __shared__ u16 sm[28672];
  int m0 = blockIdx.x * 64;
  int tid = threadIdx.x, lane = tid & 63, wave = tid >> 6;
  int col0 = lane & 15, rg = lane >> 4, kcb = rg * 16;
  int swl = (col0 & 7) << 4;
  int xrow = tid >> 2, xcq = tid & 3;      // X staging: row (0..63), 16-elem quarter
  f32x4 acc[3][4][2] = {};
  const char* Wb = (const char*)Wcat;
  char* smb = (char*)sm;

#define LOAD_X(kt_)                                                             \
  {                                                                             \
    const float4* s_ = (const float4*)(X + (size_t)(m0 + xrow) * Dn + (kt_) + xcq * 16); \
    xa0 = s_[0]; xa1 = s_[1]; xa2 = s_[2]; xa3 = s_[3];                         \
  }

  float4 xa0, xa1, xa2, xa3;
  LOAD_X(0);
  for (int kt = 0; kt < Dn; kt += 64) {
    // pack current X regs -> LDS (prev MFMA reads done via loop-tail sync)
    {
      int sw = (xrow & 7) << 4;
      *(bf16x8*)(smb + xrow * 128 + ((xcq * 32) ^ sw)) = pack8(xa0, xa1);
      *(bf16x8*)(smb + xrow * 128 + ((xcq * 32 + 16) ^ sw)) = pack8(xa2, xa3);
    }
    // T14: issue next X loads now (drain hidden under MFMA + next sync)
    if (kt + 64 < Dn) LOAD_X(kt + 64);
    // W: 48KB via gload16, pre-swizzled source (12 issues/thread)
#pragma unroll
    for (int q = 0; q < 12; ++q) {
      int c2 = wave * 12 + q;              // 0..47
      int which = c2 >> 4, idx = c2 & 15;
      int flat = idx * 1024 + lane * 16;
      int row = flat >> 7, colb = flat & 127;
      int sw = (row & 7) << 4;
      gload16(Wb + (size_t)which * 131072 + (size_t)row * 1024 + (kt << 1) + (colb ^ sw),
              smb + 8192 + which * 16384 + idx * 1024);
    }
    __syncthreads();
    bf16x8 af[4][2];
#pragma unroll
    for (int m = 0; m < 4; ++m)
#pragma unroll
      for (int kk = 0; kk < 2; ++kk)
        af[m][kk] = *(const bf16x8*)(smb + (m * 16 + col0) * 128 + ((kk * 64 + kcb) ^ swl));
#pragma unroll
    for (int which = 0; which < 3; ++which) {
      bf16x8 bfr[2][2];
#pragma unroll
      for (int n = 0; n < 2; ++n)
#pragma unroll
        for (int kk = 0; kk < 2; ++kk)
          bfr[n][kk] = *(const bf16x8*)(smb + 8192 + which * 16384 +
                                        (wave * 32 + n * 16 + col0) * 128 + ((kk * 64 + kcb) ^ swl));
#pragma unroll
      for (int kk = 0; kk < 2; ++kk)
#pragma unroll
        for (int m = 0; m < 4; ++m)
#pragma unroll
          for (int n = 0; n < 2; ++n)
            acc[which][m][n] = __builtin_amdgcn_mfma_f32_16x16x32_bf16(
                af[m][kk], bfr[n][kk], acc[which][m][n], 0, 0, 0);
    }
    __syncthreads();
  }
#undef LOAD_X

  // ---- epilogue: bounce through LDS -> full-line global stores ----
  {
#pragma unroll
    for (int n = 0; n < 2; ++n) {
      int nl = wave * 32 + n * 16 + col0;
      float bs = bk[nl];
#pragma unroll
      for (int m = 0; m < 4; ++m)
#pragma unroll
        for (int r = 0; r < 4; ++r) {
          int tl = m * 16 + rg * 4 + r;    // 0..63
          float x = acc[0][m][n][r] + bs;
          *(u16*)(smb + tl * 256 + ((nl * 2) ^ ((tl & 7) << 4))) = f2bf(x / (1.f + __expf(-x)));
        }
    }
    __syncthreads();
#pragma unroll
    for (int p = 0; p < 4; ++p) {
      int c = p * 256 + tid;               // 1024 x 16B
      int t = c >> 4, c16 = c & 15;
      bf16x8 v = *(const bf16x8*)(smb + t * 256 + ((c16 * 16) ^ ((t & 7) << 4)));
      *(bf16x8*)&Kb[(size_t)(m0 + t) * Hn + c16 * 8] = v;
    }
  }
  int bb = m0 >> 9, tt0 = m0 & (Tn - 1);
#pragma unroll
  for (int which = 1; which < 3; ++which) {
    const float* bias = (which == 1) ? bq : bv;
    u16* dst = (which == 1) ? QT : VT;
    __syncthreads();      // prev bounce's LDS reads done
#pragma unroll
    for (int n = 0; n < 2; ++n) {
      int nl = wave * 32 + n * 16 + col0;
      float bs = bias[nl];
#pragma unroll
      for (int m = 0; m < 4; ++m)
#pragma unroll
        for (int r = 0; r < 4; ++r) {
          int tl = m * 16 + rg * 4 + r;
          float x = acc[which][m][n][r] + bs;
          *(u16*)(smb + nl * 128 + ((tl * 2) ^ ((nl & 7) << 4))) = f2bf(x / (1.f + __expf(-x)));
        }
    }
    __syncthreads();
#pragma unroll
    for (int p = 0; p < 4; ++p) {
      int c = p * 256 + tid;               // 1024 x 16B
      int h = c >> 3, c8 = c & 7;
      bf16x8 v = *(const bf16x8*)(smb + h * 128 + ((c8 * 16) ^ ((h & 7) << 4)));
      *(bf16x8*)&dst[((size_t)bb * Hn + h) * Tn + tt0 + c8 * 8] = v;
    }
  }
}

// ---------- stage 2+3+4 fused: Q2 (dagq) + swapped-QK^T attention + (Pnorm+dag)@V ----------
// grid 512 (XCD-swizzled), 256 threads (4 waves).
// Phase 1: Q2 = (dagT@Q)/sqrt(H) -> LDS (16KB).  Phase 2: S^T = K Q2^T (K dbuf 64KB);
// lane-local softmax, P normalized in-register (inv = 1/s is lane-local).
// Phase 3: acco += Pnorm@V + dagT@V (single accumulator; da from L2-resident dagT).
__global__ __launch_bounds__(256, 2) void dattn(
    const u16* __restrict__ dagT, const u16* __restrict__ QT,
    const u16* __restrict__ VT, const u16* __restrict__ Kb,
    const u64* __restrict__ dbits, float* __restrict__ O) {
  __shared__ char smA[65536];   // ph1: dag[0,8K)|Q[8K,24K); ph2: K dbuf 2x32K; ph3: P[0,16K)
  __shared__ u16 smQ2[8192];    // 16KB Q2 [q][h] 64x256B swizzled (dead after bq read)

  int bid = blockIdx.x;
  int xcd = bid & 7, rst = bid >> 3;       // rst 0..63
  int bx = rst & 7, b = (rst >> 3) * 8 + xcd;
  int m0 = bx * 64;
  int tid = threadIdx.x, lane = tid & 63, wave = tid >> 6;   // 4 waves
  int col0 = lane & 15, g = lane >> 4;
  int swl = (col0 & 7) << 4;

  const char* Ab = (const char*)(dagT + (size_t)m0 * Tn);
  const char* Qb = (const char*)(QT + (size_t)b * Hn * Tn);
  const char* Vb = (const char*)(VT + (size_t)b * Hn * Tn);
  const char* Kb0 = (const char*)(Kb + (size_t)b * Tn * Hn);

  // ================= phase 1: Q2 = (dagT@Q)/sqrt(H) =================
  f32x4 accq[4][2] = {};
  for (int kt = 0; kt < Tn; kt += 64) {
#pragma unroll
    for (int q = 0; q < 2; ++q) {          // dag tile 8KB
      int ch = wave * 2 + q;
      int flat = ch * 1024 + lane * 16;
      int row = flat >> 7, colb = flat & 127;
      int sw = (row & 7) << 4;
      gload16(Ab + (size_t)row * 1024 + kt * 2 + (colb ^ sw), smA + ch * 1024);
    }
#pragma unroll
    for (int q = 0; q < 4; ++q) {          // Q tile 16KB
      int ch = wave * 4 + q;
      int flat = ch * 1024 + lane * 16;
      int row = flat >> 7, colb = flat & 127;
      int sw = (row & 7) << 4;
      gload16(Qb + (size_t)row * 1024 + kt * 2 + (colb ^ sw), smA + 8192 + ch * 1024);
    }
    __syncthreads();
    bf16x8 af[4][2], fq[2][2];
#pragma unroll
    for (int m = 0; m < 4; ++m)
#pragma unroll
      for (int kk = 0; kk < 2; ++kk)
        af[m][kk] = *(const bf16x8*)(smA + (m * 16 + col0) * 128 + ((kk * 64 + g * 16) ^ swl));
#pragma unroll
    for (int n = 0; n < 2; ++n)
#pragma unroll
      for (int kk = 0; kk < 2; ++kk)
        fq[n][kk] = *(const bf16x8*)(smA + 8192 + (wave * 32 + n * 16 + col0) * 128 + ((kk * 64 + g * 16) ^ swl));
#pragma unroll
    for (int kk = 0; kk < 2; ++kk)
#pragma unroll
      for (int m = 0; m < 4; ++m)
#pragma unroll
        for (int n = 0; n < 2; ++n)
          accq[m][n] = __builtin_amdgcn_mfma_f32_16x16x32_bf16(af[m][kk], fq[n][kk], accq[m][n], 0, 0, 0);
    __syncthreads();
  }

  // Q2 -> LDS [q][h] (scaled); accq dies here
  const float scale = 0.08838834764831845f;
#pragma unroll
  for (int m = 0; m < 4; ++m)
#pragma unroll
    for (int n = 0; n < 2; ++n)
#pragma unroll
      for (int r = 0; r < 4; ++r) {
        int q = m * 16 + g * 4 + r;
        int h = wave * 32 + n * 16 + col0;
        *(u16*)((char*)smQ2 + q * 256 + ((h * 2) ^ ((q & 7) << 4))) = f2bf(accq[m][n][r] * scale);
      }

  // ================= phase 2: S^T = K Q2^T =================
#define STAGE_K(c_, buf_)                                                      \
  {                                                                            \
    _Pragma("unroll")                                                          \
    for (int q = 0; q < 8; ++q) {                                              \
      int ch = wave * 8 + q;                                                   \
      int flat = ch * 1024 + lane * 16;                                        \
      int row = flat >> 8, colb = flat & 255;                                  \
      gload16(Kb0 + (size_t)((c_) * 128 + row) * 256 + (colb ^ ((row & 7) << 4)), \
              smA + (buf_) * 32768 + ch * 1024);                               \
    }                                                                          \
  }

  STAGE_K(0, 0);
  __syncthreads();   // Q2 visible + K chunk 0 staged

  int qrow = wave * 16 + col0;
  bf16x8 bq[4];
#pragma unroll
  for (int kk = 0; kk < 4; ++kk)
    bq[kk] = *(const bf16x8*)((char*)smQ2 + qrow * 256 + ((kk * 64 + g * 16) ^ ((qrow & 7) << 4)));
  const u64* dbq = dbits + (size_t)(m0 + qrow) * 8;
  u64 md[8];
#pragma unroll
  for (int w = 0; w < 8; ++w) md[w] = dbq[w];

  f32x4 sa[32] = {};
#pragma unroll
  for (int c = 0; c < 4; ++c) {
    if (c < 3) STAGE_K(c + 1, (c + 1) & 1);
    const char* kb = smA + (c & 1) * 32768;
#pragma unroll
    for (int t = 0; t < 8; ++t)
#pragma unroll
      for (int kk = 0; kk < 4; ++kk) {
        bf16x8 ak = *(const bf16x8*)(kb + (t * 16 + col0) * 256 + ((kk * 64 + g * 16) ^ swl));
        sa[c * 8 + t] = __builtin_amdgcn_mfma_f32_16x16x32_bf16(ak, bq[kk], sa[c * 8 + t], 0, 0, 0);
      }
    if (c < 3) __syncthreads();
  }

  // ---- mask + max (lane-local + 2 shfl) ----
  float mx = -INFINITY;
#pragma unroll
  for (int t = 0; t < 32; ++t)
#pragma unroll
    for (int r = 0; r < 4; ++r) {
      int k = t * 16 + g * 4 + r;
      float v = ((md[k >> 6] >> (k & 63)) & 1) ? sa[t][r] : -INFINITY;
      sa[t][r] = v;
      mx = fmaxf(mx, v);
    }
  mx = fmaxf(mx, __shfl_xor(mx, 16, 64));
  mx = fmaxf(mx, __shfl_xor(mx, 32, 64));
  float mm = (mx == -INFINITY) ? 0.f : mx;

  // ---- exp, row sum (lane-local after 2 shfl), NORMALIZE in-register ----
  float ev[32][4];
  float s = 0.f;
#pragma unroll
  for (int t = 0; t < 32; ++t)
#pragma unroll
    for (int r = 0; r < 4; ++r) {
      float v = sa[t][r];
      float e = (v == -INFINITY) ? 0.f : __expf(v - mm);
      ev[t][r] = e;
      s += e;
    }
  s += __shfl_xor(s, 16, 64);
  s += __shfl_xor(s, 32, 64);
  float inv = (s > 0.f) ? (1.f / s) : 0.f;
  ushort4 pk[32];
#pragma unroll
  for (int t = 0; t < 32; ++t) {
    ushort4 p;
#pragma unroll
    for (int r = 0; r < 4; ++r) ((u16*)&p)[r] = f2bf(ev[t][r] * inv);
    pk[t] = p;
  }

  // ================= phase 3: acco = Pnorm@V + dagT@V =================
  char* smP = smA;
  f32x4 acco[4][2] = {};
  int sww = (qrow & 7) << 4;

#pragma unroll
  for (int c = 0; c < 4; ++c) {
    __syncthreads();                       // all S reads of smA done / prev-chunk P reads done
#pragma unroll
    for (int tt = 0; tt < 8; ++tt)
      *(ushort4*)(smP + qrow * 256 + ((tt * 32 + g * 8) ^ sww)) = pk[c * 8 + tt];
    __syncthreads();                       // P chunk visible

#pragma unroll
    for (int kk = 0; kk < 4; ++kk) {
      bf16x8 pa[4], da[4], vb[2];
#pragma unroll
      for (int m = 0; m < 4; ++m) {
        int row = m * 16 + col0;           // 64 q-rows
        pa[m] = *(const bf16x8*)(smP + row * 256 + ((kk * 64 + g * 16) ^ ((row & 7) << 4)));
        da[m] = *(const bf16x8*)(Ab + (size_t)row * 1024 + c * 256 + kk * 64 + g * 16);
      }
#pragma unroll
      for (int n = 0; n < 2; ++n)
        vb[n] = *(const bf16x8*)(Vb + (size_t)(wave * 32 + n * 16 + col0) * 1024 + c * 256 + kk * 64 + g * 16);
#pragma unroll
      for (int m = 0; m < 4; ++m)
#pragma unroll
        for (int n = 0; n < 2; ++n) {
          acco[m][n] = __builtin_amdgcn_mfma_f32_16x16x32_bf16(pa[m], vb[n], acco[m][n], 0, 0, 0);
          acco[m][n] = __builtin_amdgcn_mfma_f32_16x16x32_bf16(da[m], vb[n], acco[m][n], 0, 0, 0);
        }
    }
  }

  // ---- epilogue: O = acco ----
#pragma unroll
  for (int m = 0; m < 4; ++m)
#pragma unroll
    for (int r = 0; r < 4; ++r) {
      int i = m0 + m * 16 + g * 4 + r;
#pragma unroll
      for (int n = 0; n < 2; ++n) {
        int h = wave * 32 + n * 16 + col0;
        O[((size_t)b * Tn + i) * Hn + h] = acco[m][n][r];
      }
    }
#undef STAGE_K
}

extern "C" void kernel_launch(void* const* d_in, const int* in_sizes, int n_in,
                              void* d_out, int out_size, void* d_ws, size_t ws_size,
                              hipStream_t stream) {
  const float* X   = (const float*)d_in[0];
  const float* dag = (const float*)d_in[1];
  const float* Wk  = (const float*)d_in[2];
  const float* bk  = (const float*)d_in[3];
  const float* Wq  = (const float*)d_in[4];
  const float* bq  = (const float*)d_in[5];
  const float* Wv  = (const float*)d_in[6];
  const float* bv  = (const float*)d_in[7];
  float* O = (float*)d_out;

  char* ws = (char*)d_ws;
  u16* Wcat = (u16*)(ws);                 //    393,216
  u16* dagT = (u16*)(ws + 393216);        //    524,288
  u64* dbits= (u64*)(ws + 917504);        //     32,768
  u16* Kb   = (u16*)(ws + 950272);        //  8,388,608
  u16* QT   = (u16*)(ws + 9338880);       //  8,388,608
  u16* VT   = (u16*)(ws + 17727488);      //  8,388,608  (end 26,116,096)

  conv_w3<<<192, 256, 0, stream>>>((const float4*)Wk, (const float4*)Wq,
                                   (const float4*)Wv, (ushort4*)Wcat);
  dag_tr<<<64, 256, 0, stream>>>(dag, dagT, dbits);

  qkv3<<<BT / 64, 256, 0, stream>>>(X, Wcat, bk, bq, bv, Kb, QT, VT);
  dattn<<<512, 256, 0, stream>>>(dagT, QT, VT, Kb, dbits, O);
}

// Round 15
// 70.516 us; speedup vs baseline: 1.1292x; 1.1292x over previous
//
#include <hip/hip_runtime.h>
#include <hip/hip_bf16.h>

#define Bn 64
#define Tn 512
#define Dn 512
#define Hn 128
#define BT (Bn*Tn)

typedef unsigned short u16;
typedef unsigned long long u64;
typedef __attribute__((ext_vector_type(8))) short bf16x8;
typedef __attribute__((ext_vector_type(4))) float f32x4;

__device__ __forceinline__ u16 f2bf(float f) {
  union { float f; unsigned u; } v; v.f = f;
  unsigned r = (v.u + 0x7FFFu + ((v.u >> 16) & 1u)) >> 16;
  return (u16)r;
}

__device__ __forceinline__ bf16x8 pack8(float4 a, float4 b) {
  bf16x8 o;
  o[0] = (short)f2bf(a.x); o[1] = (short)f2bf(a.y);
  o[2] = (short)f2bf(a.z); o[3] = (short)f2bf(a.w);
  o[4] = (short)f2bf(b.x); o[5] = (short)f2bf(b.y);
  o[6] = (short)f2bf(b.z); o[7] = (short)f2bf(b.w);
  return o;
}

// async global->LDS, 16B/lane; LDS dest = wave-uniform base (+lane*16 by HW)
__device__ __forceinline__ void gload16(const void* g, void* lds) {
  __builtin_amdgcn_global_load_lds(
      (const __attribute__((address_space(1))) unsigned int*)g,
      (__attribute__((address_space(3))) unsigned int*)lds, 16, 0, 0);
}

// ---------- prep: all three W -> bf16 (one launch) ----------
__global__ __launch_bounds__(256) void conv_w3(const float4* __restrict__ Wk,
                                               const float4* __restrict__ Wq,
                                               const float4* __restrict__ Wv,
                                               ushort4* __restrict__ out) {
  int idx = blockIdx.x * 256 + threadIdx.x;        // 3 * 16384
  int which = idx >> 14, j = idx & 16383;
  const float4* src = (which == 0) ? Wk : (which == 1) ? Wq : Wv;
  float4 v = src[j];
  ushort4 o; o.x = f2bf(v.x); o.y = f2bf(v.y); o.z = f2bf(v.z); o.w = f2bf(v.w);
  out[idx] = o;
}

// ---------- prep: dag transpose + bf16 + mask bits (fused) ----------
__global__ __launch_bounds__(256) void dag_tr(const float* __restrict__ dag,
                                              u16* __restrict__ dagT,
                                              u64* __restrict__ bits) {
  __shared__ float s[64][65];
  int bx = blockIdx.x & 7, by = blockIdx.x >> 3;
  int r0 = by * 64, c0 = bx * 64;
  int t = threadIdx.x;
  int c4 = t & 15, rr = t >> 4;
#pragma unroll
  for (int q = 0; q < 4; ++q) {
    int r = rr + q * 16;
    float4 v = *(const float4*)&dag[(size_t)(r0 + r) * Tn + c0 + c4 * 4];
    s[c4 * 4 + 0][r] = v.x; s[c4 * 4 + 1][r] = v.y;
    s[c4 * 4 + 2][r] = v.z; s[c4 * 4 + 3][r] = v.w;
  }
  __syncthreads();
#pragma unroll
  for (int q = 0; q < 4; ++q) {
    int il = rr + q * 16;
    ushort4 o;
    u64 b4 = 0;
#pragma unroll
    for (int r = 0; r < 4; ++r) {
      float v = s[il][c4 * 4 + r];
      ((u16*)&o)[r] = f2bf(v);
      b4 |= (u64)(v != 0.f) << (c4 * 4 + r);
    }
    *(ushort4*)&dagT[(size_t)(c0 + il) * Tn + r0 + c4 * 4] = o;
    b4 |= __shfl_xor(b4, 1, 64);
    b4 |= __shfl_xor(b4, 2, 64);
    b4 |= __shfl_xor(b4, 4, 64);
    b4 |= __shfl_xor(b4, 8, 64);
    if (c4 == 0) bits[(size_t)(c0 + il) * 8 + (r0 >> 6)] = b4;
  }
}

// ---------- stage 1: K,Q,V = swish(X W^T + b); BM=64, 2 blocks/CU, T14 X-prefetch ----------
// grid BT/64 = 512, 256 threads (4 waves; wave w owns h-cols w*32..w*32+31).
__global__ __launch_bounds__(256, 2) void qkv3(
    const float* __restrict__ X, const u16* __restrict__ Wcat,
    const float* __restrict__ bk, const float* __restrict__ bq,
    const float* __restrict__ bv,
    u16* __restrict__ Kb, u16* __restrict__ QT, u16* __restrict__ VT) {
  __shared__ u16 sm[28672];
  int m0 = blockIdx.x * 64;
  int tid = threadIdx.x, lane = tid & 63, wave = tid >> 6;
  int col0 = lane & 15, rg = lane >> 4, kcb = rg * 16;
  int swl = (col0 & 7) << 4;
  int xrow = tid >> 2, xcq = tid & 3;      // X staging: row (0..63), 16-elem quarter
  f32x4 acc[3][4][2] = {};
  const char* Wb = (const char*)Wcat;
  char* smb = (char*)sm;

#define LOAD_X(kt_)                                                             \
  {                                                                             \
    const float4* s_ = (const float4*)(X + (size_t)(m0 + xrow) * Dn + (kt_) + xcq * 16); \
    xa0 = s_[0]; xa1 = s_[1]; xa2 = s_[2]; xa3 = s_[3];                         \
  }

  float4 xa0, xa1, xa2, xa3;
  LOAD_X(0);
  for (int kt = 0; kt < Dn; kt += 64) {
    // pack current X regs -> LDS (prev MFMA reads done via loop-tail sync)
    {
      int sw = (xrow & 7) << 4;
      *(bf16x8*)(smb + xrow * 128 + ((xcq * 32) ^ sw)) = pack8(xa0, xa1);
      *(bf16x8*)(smb + xrow * 128 + ((xcq * 32 + 16) ^ sw)) = pack8(xa2, xa3);
    }
    // T14: issue next X loads now (drain hidden under MFMA + next sync)
    if (kt + 64 < Dn) LOAD_X(kt + 64);
    // W: 48KB via gload16, pre-swizzled source (12 issues/thread)
#pragma unroll
    for (int q = 0; q < 12; ++q) {
      int c2 = wave * 12 + q;              // 0..47
      int which = c2 >> 4, idx = c2 & 15;
      int flat = idx * 1024 + lane * 16;
      int row = flat >> 7, colb = flat & 127;
      int sw = (row & 7) << 4;
      gload16(Wb + (size_t)which * 131072 + (size_t)row * 1024 + (kt << 1) + (colb ^ sw),
              smb + 8192 + which * 16384 + idx * 1024);
    }
    __syncthreads();
    bf16x8 af[4][2];
#pragma unroll
    for (int m = 0; m < 4; ++m)
#pragma unroll
      for (int kk = 0; kk < 2; ++kk)
        af[m][kk] = *(const bf16x8*)(smb + (m * 16 + col0) * 128 + ((kk * 64 + kcb) ^ swl));
#pragma unroll
    for (int which = 0; which < 3; ++which) {
      bf16x8 bfr[2][2];
#pragma unroll
      for (int n = 0; n < 2; ++n)
#pragma unroll
        for (int kk = 0; kk < 2; ++kk)
          bfr[n][kk] = *(const bf16x8*)(smb + 8192 + which * 16384 +
                                        (wave * 32 + n * 16 + col0) * 128 + ((kk * 64 + kcb) ^ swl));
#pragma unroll
      for (int kk = 0; kk < 2; ++kk)
#pragma unroll
        for (int m = 0; m < 4; ++m)
#pragma unroll
          for (int n = 0; n < 2; ++n)
            acc[which][m][n] = __builtin_amdgcn_mfma_f32_16x16x32_bf16(
                af[m][kk], bfr[n][kk], acc[which][m][n], 0, 0, 0);
    }
    __syncthreads();
  }
#undef LOAD_X

  // ---- epilogue: bounce through LDS -> full-line global stores ----
  {
#pragma unroll
    for (int n = 0; n < 2; ++n) {
      int nl = wave * 32 + n * 16 + col0;
      float bs = bk[nl];
#pragma unroll
      for (int m = 0; m < 4; ++m)
#pragma unroll
        for (int r = 0; r < 4; ++r) {
          int tl = m * 16 + rg * 4 + r;    // 0..63
          float x = acc[0][m][n][r] + bs;
          *(u16*)(smb + tl * 256 + ((nl * 2) ^ ((tl & 7) << 4))) = f2bf(x / (1.f + __expf(-x)));
        }
    }
    __syncthreads();
#pragma unroll
    for (int p = 0; p < 4; ++p) {
      int c = p * 256 + tid;               // 1024 x 16B
      int t = c >> 4, c16 = c & 15;
      bf16x8 v = *(const bf16x8*)(smb + t * 256 + ((c16 * 16) ^ ((t & 7) << 4)));
      *(bf16x8*)&Kb[(size_t)(m0 + t) * Hn + c16 * 8] = v;
    }
  }
  int bb = m0 >> 9, tt0 = m0 & (Tn - 1);
#pragma unroll
  for (int which = 1; which < 3; ++which) {
    const float* bias = (which == 1) ? bq : bv;
    u16* dst = (which == 1) ? QT : VT;
    __syncthreads();      // prev bounce's LDS reads done
#pragma unroll
    for (int n = 0; n < 2; ++n) {
      int nl = wave * 32 + n * 16 + col0;
      float bs = bias[nl];
#pragma unroll
      for (int m = 0; m < 4; ++m)
#pragma unroll
        for (int r = 0; r < 4; ++r) {
          int tl = m * 16 + rg * 4 + r;
          float x = acc[which][m][n][r] + bs;
          *(u16*)(smb + nl * 128 + ((tl * 2) ^ ((nl & 7) << 4))) = f2bf(x / (1.f + __expf(-x)));
        }
    }
    __syncthreads();
#pragma unroll
    for (int p = 0; p < 4; ++p) {
      int c = p * 256 + tid;               // 1024 x 16B
      int h = c >> 3, c8 = c & 7;
      bf16x8 v = *(const bf16x8*)(smb + h * 128 + ((c8 * 16) ^ ((h & 7) << 4)));
      *(bf16x8*)&dst[((size_t)bb * Hn + h) * Tn + tt0 + c8 * 8] = v;
    }
  }
}

// ---------- stage 2+3+4 fused: Q2 (dagq) + swapped-QK^T attention, dag folded into P ----------
// grid 512 (XCD-swizzled), 256 threads (4 waves).
// Phase 1: Q2 = (dagT@Q)/sqrt(H) -> LDS (16KB).
// Phase 2: S^T = K Q2^T (K dbuf 64KB); lane-local softmax; P' = e*inv + dagbit (bf16).
// Phase 3: O = P'@V  (single MFMA stream; no dag matmul, no linv).
__global__ __launch_bounds__(256, 2) void dattn(
    const u16* __restrict__ dagT, const u16* __restrict__ QT,
    const u16* __restrict__ VT, const u16* __restrict__ Kb,
    const u64* __restrict__ dbits, float* __restrict__ O) {
  __shared__ char smA[65536];   // ph1: dag[0,8K)|Q[8K,24K); ph2: K dbuf 2x32K; ph3: P[0,16K)
  __shared__ u16 smQ2[8192];    // 16KB Q2 [q][h] 64x256B swizzled (dead after bq read)

  int bid = blockIdx.x;
  int xcd = bid & 7, rst = bid >> 3;       // rst 0..63
  int bx = rst & 7, b = (rst >> 3) * 8 + xcd;
  int m0 = bx * 64;
  int tid = threadIdx.x, lane = tid & 63, wave = tid >> 6;   // 4 waves
  int col0 = lane & 15, g = lane >> 4;
  int swl = (col0 & 7) << 4;

  const char* Ab = (const char*)(dagT + (size_t)m0 * Tn);
  const char* Qb = (const char*)(QT + (size_t)b * Hn * Tn);
  const char* Vb = (const char*)(VT + (size_t)b * Hn * Tn);
  const char* Kb0 = (const char*)(Kb + (size_t)b * Tn * Hn);

  // ================= phase 1: Q2 = (dagT@Q)/sqrt(H) =================
  f32x4 accq[4][2] = {};
  for (int kt = 0; kt < Tn; kt += 64) {
#pragma unroll
    for (int q = 0; q < 2; ++q) {          // dag tile 8KB
      int ch = wave * 2 + q;
      int flat = ch * 1024 + lane * 16;
      int row = flat >> 7, colb = flat & 127;
      int sw = (row & 7) << 4;
      gload16(Ab + (size_t)row * 1024 + kt * 2 + (colb ^ sw), smA + ch * 1024);
    }
#pragma unroll
    for (int q = 0; q < 4; ++q) {          // Q tile 16KB
      int ch = wave * 4 + q;
      int flat = ch * 1024 + lane * 16;
      int row = flat >> 7, colb = flat & 127;
      int sw = (row & 7) << 4;
      gload16(Qb + (size_t)row * 1024 + kt * 2 + (colb ^ sw), smA + 8192 + ch * 1024);
    }
    __syncthreads();
    bf16x8 af[4][2], fq[2][2];
#pragma unroll
    for (int m = 0; m < 4; ++m)
#pragma unroll
      for (int kk = 0; kk < 2; ++kk)
        af[m][kk] = *(const bf16x8*)(smA + (m * 16 + col0) * 128 + ((kk * 64 + g * 16) ^ swl));
#pragma unroll
    for (int n = 0; n < 2; ++n)
#pragma unroll
      for (int kk = 0; kk < 2; ++kk)
        fq[n][kk] = *(const bf16x8*)(smA + 8192 + (wave * 32 + n * 16 + col0) * 128 + ((kk * 64 + g * 16) ^ swl));
#pragma unroll
    for (int kk = 0; kk < 2; ++kk)
#pragma unroll
      for (int m = 0; m < 4; ++m)
#pragma unroll
        for (int n = 0; n < 2; ++n)
          accq[m][n] = __builtin_amdgcn_mfma_f32_16x16x32_bf16(af[m][kk], fq[n][kk], accq[m][n], 0, 0, 0);
    __syncthreads();
  }

  // Q2 -> LDS [q][h] (scaled); accq dies here
  const float scale = 0.08838834764831845f;
#pragma unroll
  for (int m = 0; m < 4; ++m)
#pragma unroll
    for (int n = 0; n < 2; ++n)
#pragma unroll
      for (int r = 0; r < 4; ++r) {
        int q = m * 16 + g * 4 + r;
        int h = wave * 32 + n * 16 + col0;
        *(u16*)((char*)smQ2 + q * 256 + ((h * 2) ^ ((q & 7) << 4))) = f2bf(accq[m][n][r] * scale);
      }

  // ================= phase 2: S^T = K Q2^T =================
#define STAGE_K(c_, buf_)                                                      \
  {                                                                            \
    _Pragma("unroll")                                                          \
    for (int q = 0; q < 8; ++q) {                                              \
      int ch = wave * 8 + q;                                                   \
      int flat = ch * 1024 + lane * 16;                                        \
      int row = flat >> 8, colb = flat & 255;                                  \
      gload16(Kb0 + (size_t)((c_) * 128 + row) * 256 + (colb ^ ((row & 7) << 4)), \
              smA + (buf_) * 32768 + ch * 1024);                               \
    }                                                                          \
  }

  STAGE_K(0, 0);
  __syncthreads();   // Q2 visible + K chunk 0 staged

  int qrow = wave * 16 + col0;
  bf16x8 bq[4];
#pragma unroll
  for (int kk = 0; kk < 4; ++kk)
    bq[kk] = *(const bf16x8*)((char*)smQ2 + qrow * 256 + ((kk * 64 + g * 16) ^ ((qrow & 7) << 4)));
  const u64* dbq = dbits + (size_t)(m0 + qrow) * 8;
  u64 md[8];
#pragma unroll
  for (int w = 0; w < 8; ++w) md[w] = dbq[w];

  f32x4 sa[32] = {};
#pragma unroll
  for (int c = 0; c < 4; ++c) {
    if (c < 3) STAGE_K(c + 1, (c + 1) & 1);
    const char* kb = smA + (c & 1) * 32768;
#pragma unroll
    for (int t = 0; t < 8; ++t)
#pragma unroll
      for (int kk = 0; kk < 4; ++kk) {
        bf16x8 ak = *(const bf16x8*)(kb + (t * 16 + col0) * 256 + ((kk * 64 + g * 16) ^ swl));
        sa[c * 8 + t] = __builtin_amdgcn_mfma_f32_16x16x32_bf16(ak, bq[kk], sa[c * 8 + t], 0, 0, 0);
      }
    if (c < 3) __syncthreads();
  }

  // ---- mask + max (lane-local + 2 shfl) ----
  float mx = -INFINITY;
#pragma unroll
  for (int t = 0; t < 32; ++t)
#pragma unroll
    for (int r = 0; r < 4; ++r) {
      int k = t * 16 + g * 4 + r;
      float v = ((md[k >> 6] >> (k & 63)) & 1) ? sa[t][r] : -INFINITY;
      sa[t][r] = v;
      mx = fmaxf(mx, v);
    }
  mx = fmaxf(mx, __shfl_xor(mx, 16, 64));
  mx = fmaxf(mx, __shfl_xor(mx, 32, 64));
  float mm = (mx == -INFINITY) ? 0.f : mx;

  // ---- exp in place, row sum (lane-local after 2 shfl) ----
  float s = 0.f;
#pragma unroll
  for (int t = 0; t < 32; ++t)
#pragma unroll
    for (int r = 0; r < 4; ++r) {
      float v = sa[t][r];
      float e = (v == -INFINITY) ? 0.f : __expf(v - mm);
      sa[t][r] = e;
      s += e;
    }
  s += __shfl_xor(s, 16, 64);
  s += __shfl_xor(s, 32, 64);
  float inv = (s > 0.f) ? (1.f / s) : 0.f;

  // ---- pack P' = e*inv + dagbit (dag@V folded into the P matmul) ----
  ushort4 pk[32];
#pragma unroll
  for (int t = 0; t < 32; ++t) {
    ushort4 p;
#pragma unroll
    for (int r = 0; r < 4; ++r) {
      int k = t * 16 + g * 4 + r;
      float d = (float)((md[k >> 6] >> (k & 63)) & 1);
      ((u16*)&p)[r] = f2bf(sa[t][r] * inv + d);
    }
    pk[t] = p;
  }

  // ================= phase 3: O = P'@V =================
  char* smP = smA;
  f32x4 acco[4][2] = {};
  int sww = (qrow & 7) << 4;

#pragma unroll
  for (int c = 0; c < 4; ++c) {
    __syncthreads();                       // all S reads of smA done / prev-chunk P reads done
#pragma unroll
    for (int tt = 0; tt < 8; ++tt)
      *(ushort4*)(smP + qrow * 256 + ((tt * 32 + g * 8) ^ sww)) = pk[c * 8 + tt];
    __syncthreads();                       // P chunk visible

#pragma unroll
    for (int kk = 0; kk < 4; ++kk) {
      bf16x8 pa[4], vb[2];
#pragma unroll
      for (int m = 0; m < 4; ++m) {
        int row = m * 16 + col0;           // 64 q-rows
        pa[m] = *(const bf16x8*)(smP + row * 256 + ((kk * 64 + g * 16) ^ ((row & 7) << 4)));
      }
#pragma unroll
      for (int n = 0; n < 2; ++n)
        vb[n] = *(const bf16x8*)(Vb + (size_t)(wave * 32 + n * 16 + col0) * 1024 + c * 256 + kk * 64 + g * 16);
#pragma unroll
      for (int m = 0; m < 4; ++m)
#pragma unroll
        for (int n = 0; n < 2; ++n)
          acco[m][n] = __builtin_amdgcn_mfma_f32_16x16x32_bf16(pa[m], vb[n], acco[m][n], 0, 0, 0);
    }
  }

  // ---- epilogue: O = acco ----
#pragma unroll
  for (int m = 0; m < 4; ++m)
#pragma unroll
    for (int r = 0; r < 4; ++r) {
      int i = m0 + m * 16 + g * 4 + r;
#pragma unroll
      for (int n = 0; n < 2; ++n) {
        int h = wave * 32 + n * 16 + col0;
        O[((size_t)b * Tn + i) * Hn + h] = acco[m][n][r];
      }
    }
#undef STAGE_K
}

extern "C" void kernel_launch(void* const* d_in, const int* in_sizes, int n_in,
                              void* d_out, int out_size, void* d_ws, size_t ws_size,
                              hipStream_t stream) {
  const float* X   = (const float*)d_in[0];
  const float* dag = (const float*)d_in[1];
  const float* Wk  = (const float*)d_in[2];
  const float* bk  = (const float*)d_in[3];
  const float* Wq  = (const float*)d_in[4];
  const float* bq  = (const float*)d_in[5];
  const float* Wv  = (const float*)d_in[6];
  const float* bv  = (const float*)d_in[7];
  float* O = (float*)d_out;

  char* ws = (char*)d_ws;
  u16* Wcat = (u16*)(ws);                 //    393,216
  u16* dagT = (u16*)(ws + 393216);        //    524,288
  u64* dbits= (u64*)(ws + 917504);        //     32,768
  u16* Kb   = (u16*)(ws + 950272);        //  8,388,608
  u16* QT   = (u16*)(ws + 9338880);       //  8,388,608
  u16* VT   = (u16*)(ws + 17727488);      //  8,388,608  (end 26,116,096)

  conv_w3<<<192, 256, 0, stream>>>((const float4*)Wk, (const float4*)Wq,
                                   (const float4*)Wv, (ushort4*)Wcat);
  dag_tr<<<64, 256, 0, stream>>>(dag, dagT, dbits);

  qkv3<<<BT / 64, 256, 0, stream>>>(X, Wcat, bk, bq, bv, Kb, QT, VT);
  dattn<<<512, 256, 0, stream>>>(dagT, QT, VT, Kb, dbits, O);
}

// Round 16
// 65.835 us; speedup vs baseline: 1.2095x; 1.0711x over previous
//
#include <hip/hip_runtime.h>
#include <hip/hip_bf16.h>

#define Bn 64
#define Tn 512
#define Dn 512
#define Hn 128
#define BT (Bn*Tn)

typedef unsigned short u16;
typedef unsigned long long u64;
typedef __attribute__((ext_vector_type(8))) short bf16x8;
typedef __attribute__((ext_vector_type(4))) float f32x4;

__device__ __forceinline__ u16 f2bf(float f) {
  union { float f; unsigned u; } v; v.f = f;
  unsigned r = (v.u + 0x7FFFu + ((v.u >> 16) & 1u)) >> 16;
  return (u16)r;
}

__device__ __forceinline__ bf16x8 pack8(float4 a, float4 b) {
  bf16x8 o;
  o[0] = (short)f2bf(a.x); o[1] = (short)f2bf(a.y);
  o[2] = (short)f2bf(a.z); o[3] = (short)f2bf(a.w);
  o[4] = (short)f2bf(b.x); o[5] = (short)f2bf(b.y);
  o[6] = (short)f2bf(b.z); o[7] = (short)f2bf(b.w);
  return o;
}

// async global->LDS, 16B/lane; LDS dest = wave-uniform base (+lane*16 by HW)
__device__ __forceinline__ void gload16(const void* g, void* lds) {
  __builtin_amdgcn_global_load_lds(
      (const __attribute__((address_space(1))) unsigned int*)g,
      (__attribute__((address_space(3))) unsigned int*)lds, 16, 0, 0);
}

// ---------- prep (merged): blocks 0..191 = W->bf16; blocks 192..255 = dag transpose+bits ----------
__global__ __launch_bounds__(256) void prep(
    const float4* __restrict__ Wk, const float4* __restrict__ Wq,
    const float4* __restrict__ Wv, ushort4* __restrict__ Wcat,
    const float* __restrict__ dag, u16* __restrict__ dagT,
    u64* __restrict__ bits) {
  __shared__ float s[64][65];
  if (blockIdx.x < 192) {
    int idx = blockIdx.x * 256 + threadIdx.x;        // 3 * 16384
    int which = idx >> 14, j = idx & 16383;
    const float4* src = (which == 0) ? Wk : (which == 1) ? Wq : Wv;
    float4 v = src[j];
    ushort4 o; o.x = f2bf(v.x); o.y = f2bf(v.y); o.z = f2bf(v.z); o.w = f2bf(v.w);
    Wcat[idx] = o;
  } else {
    int bid = blockIdx.x - 192;                      // 0..63
    int bx = bid & 7, by = bid >> 3;
    int r0 = by * 64, c0 = bx * 64;
    int t = threadIdx.x;
    int c4 = t & 15, rr = t >> 4;
#pragma unroll
    for (int q = 0; q < 4; ++q) {
      int r = rr + q * 16;
      float4 v = *(const float4*)&dag[(size_t)(r0 + r) * Tn + c0 + c4 * 4];
      s[c4 * 4 + 0][r] = v.x; s[c4 * 4 + 1][r] = v.y;
      s[c4 * 4 + 2][r] = v.z; s[c4 * 4 + 3][r] = v.w;
    }
    __syncthreads();
#pragma unroll
    for (int q = 0; q < 4; ++q) {
      int il = rr + q * 16;
      ushort4 o;
      u64 b4 = 0;
#pragma unroll
      for (int r = 0; r < 4; ++r) {
        float v = s[il][c4 * 4 + r];
        ((u16*)&o)[r] = f2bf(v);
        b4 |= (u64)(v != 0.f) << (c4 * 4 + r);
      }
      *(ushort4*)&dagT[(size_t)(c0 + il) * Tn + r0 + c4 * 4] = o;
      b4 |= __shfl_xor(b4, 1, 64);
      b4 |= __shfl_xor(b4, 2, 64);
      b4 |= __shfl_xor(b4, 4, 64);
      b4 |= __shfl_xor(b4, 8, 64);
      if (c4 == 0) bits[(size_t)(c0 + il) * 8 + (r0 >> 6)] = b4;
    }
  }
}

// ---------- stage 1: K,Q,V = swish(X W^T + b); BM=64, 2 blocks/CU, XCD-swizzled by b ----------
// grid 512, 256 threads (4 waves; wave w owns h-cols w*32..w*32+31).
// Block bid -> xcd=bid&7, idx=bid>>3: b=(idx&7)*8+xcd, rowblk=idx>>3 — all 8 row-blocks
// of batch b land on XCD b%8 (same as dattn's consumers -> K/Q/V stay in that L2).
__global__ __launch_bounds__(256, 2) void qkv3(
    const float* __restrict__ X, const u16* __restrict__ Wcat,
    const float* __restrict__ bk, const float* __restrict__ bq,
    const float* __restrict__ bv,
    u16* __restrict__ Kb, u16* __restrict__ QT, u16* __restrict__ VT) {
  __shared__ u16 sm[28672];
  int bid = blockIdx.x;
  int xcd = bid & 7, idx = bid >> 3;       // idx 0..63
  int b = (idx & 7) * 8 + xcd;             // 0..63
  int rowblk = idx >> 3;                   // 0..7
  int m0 = b * Tn + rowblk * 64;           // global token row
  int tid = threadIdx.x, lane = tid & 63, wave = tid >> 6;
  int col0 = lane & 15, rg = lane >> 4, kcb = rg * 16;
  int swl = (col0 & 7) << 4;
  int xrow = tid >> 2, xcq = tid & 3;      // X staging: row (0..63), 16-elem quarter
  f32x4 acc[3][4][2] = {};
  const char* Wb = (const char*)Wcat;
  char* smb = (char*)sm;

#define LOAD_X(kt_)                                                             \
  {                                                                             \
    const float4* s_ = (const float4*)(X + (size_t)(m0 + xrow) * Dn + (kt_) + xcq * 16); \
    xa0 = s_[0]; xa1 = s_[1]; xa2 = s_[2]; xa3 = s_[3];                         \
  }

  float4 xa0, xa1, xa2, xa3;
  LOAD_X(0);
  for (int kt = 0; kt < Dn; kt += 64) {
    // pack current X regs -> LDS (prev MFMA reads done via loop-tail sync)
    {
      int sw = (xrow & 7) << 4;
      *(bf16x8*)(smb + xrow * 128 + ((xcq * 32) ^ sw)) = pack8(xa0, xa1);
      *(bf16x8*)(smb + xrow * 128 + ((xcq * 32 + 16) ^ sw)) = pack8(xa2, xa3);
    }
    // T14: issue next X loads now (drain hidden under MFMA + next sync)
    if (kt + 64 < Dn) LOAD_X(kt + 64);
    // W: 48KB via gload16, pre-swizzled source (12 issues/thread)
#pragma unroll
    for (int q = 0; q < 12; ++q) {
      int c2 = wave * 12 + q;              // 0..47
      int which = c2 >> 4, widx = c2 & 15;
      int flat = widx * 1024 + lane * 16;
      int row = flat >> 7, colb = flat & 127;
      int sw = (row & 7) << 4;
      gload16(Wb + (size_t)which * 131072 + (size_t)row * 1024 + (kt << 1) + (colb ^ sw),
              smb + 8192 + which * 16384 + widx * 1024);
    }
    __syncthreads();
    bf16x8 af[4][2];
#pragma unroll
    for (int m = 0; m < 4; ++m)
#pragma unroll
      for (int kk = 0; kk < 2; ++kk)
        af[m][kk] = *(const bf16x8*)(smb + (m * 16 + col0) * 128 + ((kk * 64 + kcb) ^ swl));
#pragma unroll
    for (int which = 0; which < 3; ++which) {
      bf16x8 bfr[2][2];
#pragma unroll
      for (int n = 0; n < 2; ++n)
#pragma unroll
        for (int kk = 0; kk < 2; ++kk)
          bfr[n][kk] = *(const bf16x8*)(smb + 8192 + which * 16384 +
                                        (wave * 32 + n * 16 + col0) * 128 + ((kk * 64 + kcb) ^ swl));
#pragma unroll
      for (int kk = 0; kk < 2; ++kk)
#pragma unroll
        for (int m = 0; m < 4; ++m)
#pragma unroll
          for (int n = 0; n < 2; ++n)
            acc[which][m][n] = __builtin_amdgcn_mfma_f32_16x16x32_bf16(
                af[m][kk], bfr[n][kk], acc[which][m][n], 0, 0, 0);
    }
    __syncthreads();
  }
#undef LOAD_X

  // ---- epilogue: K/Q/V bounced to DISJOINT LDS regions, ONE sync, full-line stores ----
  // K [0,16K) layout [t][h] 256B rows; Q [16K,32K), V [32K,48K) layout [h][t] 128B rows.
  {
#pragma unroll
    for (int n = 0; n < 2; ++n) {
      int nl = wave * 32 + n * 16 + col0;
      float bsk = bk[nl], bsq = bq[nl], bsv = bv[nl];
#pragma unroll
      for (int m = 0; m < 4; ++m)
#pragma unroll
        for (int r = 0; r < 4; ++r) {
          int tl = m * 16 + rg * 4 + r;    // 0..63
          float xk = acc[0][m][n][r] + bsk;
          float xq = acc[1][m][n][r] + bsq;
          float xv = acc[2][m][n][r] + bsv;
          *(u16*)(smb + tl * 256 + ((nl * 2) ^ ((tl & 7) << 4))) = f2bf(xk / (1.f + __expf(-xk)));
          *(u16*)(smb + 16384 + nl * 128 + ((tl * 2) ^ ((nl & 7) << 4))) = f2bf(xq / (1.f + __expf(-xq)));
          *(u16*)(smb + 32768 + nl * 128 + ((tl * 2) ^ ((nl & 7) << 4))) = f2bf(xv / (1.f + __expf(-xv)));
        }
    }
    __syncthreads();
    int tt0 = rowblk * 64;
#pragma unroll
    for (int p = 0; p < 4; ++p) {
      int c = p * 256 + tid;               // 1024 x 16B
      int t = c >> 4, c16 = c & 15;
      *(bf16x8*)&Kb[(size_t)(m0 + t) * Hn + c16 * 8] =
          *(const bf16x8*)(smb + t * 256 + ((c16 * 16) ^ ((t & 7) << 4)));
    }
#pragma unroll
    for (int p = 0; p < 4; ++p) {
      int c = p * 256 + tid;               // 1024 x 16B
      int h = c >> 3, c8 = c & 7;
      *(bf16x8*)&QT[((size_t)b * Hn + h) * Tn + tt0 + c8 * 8] =
          *(const bf16x8*)(smb + 16384 + h * 128 + ((c8 * 16) ^ ((h & 7) << 4)));
      *(bf16x8*)&VT[((size_t)b * Hn + h) * Tn + tt0 + c8 * 8] =
          *(const bf16x8*)(smb + 32768 + h * 128 + ((c8 * 16) ^ ((h & 7) << 4)));
    }
  }
}

// ---------- stage 2+3+4 fused: Q2 (dagq) + swapped-QK^T attention, dag folded into P ----------
// grid 512 (XCD-swizzled), 256 threads (4 waves).
// Phase 1: Q2 = (dagT@Q)/sqrt(H) -> LDS (16KB).
// Phase 2: S^T = K Q2^T (K dbuf 64KB); lane-local softmax; P' = e*inv + dagbit (bf16).
// Phase 3: O = P'@V with P DOUBLE-BUFFERED in dead K-buf0 ([0,16K)/[16K,32K)):
//   write P(c+1) overlaps MFMA on P(c); 5 barriers instead of 8.
__global__ __launch_bounds__(256, 2) void dattn(
    const u16* __restrict__ dagT, const u16* __restrict__ QT,
    const u16* __restrict__ VT, const u16* __restrict__ Kb,
    const u64* __restrict__ dbits, float* __restrict__ O) {
  __shared__ char smA[65536];   // ph1: dag[0,8K)|Q[8K,24K); ph2: K dbuf 2x32K; ph3: P dbuf 2x16K in [0,32K)
  __shared__ u16 smQ2[8192];    // 16KB Q2 [q][h] 64x256B swizzled (dead after bq read)

  int bid = blockIdx.x;
  int xcd = bid & 7, rst = bid >> 3;       // rst 0..63
  int bx = rst & 7, b = (rst >> 3) * 8 + xcd;
  int m0 = bx * 64;
  int tid = threadIdx.x, lane = tid & 63, wave = tid >> 6;   // 4 waves
  int col0 = lane & 15, g = lane >> 4;
  int swl = (col0 & 7) << 4;

  const char* Ab = (const char*)(dagT + (size_t)m0 * Tn);
  const char* Qb = (const char*)(QT + (size_t)b * Hn * Tn);
  const char* Vb = (const char*)(VT + (size_t)b * Hn * Tn);
  const char* Kb0 = (const char*)(Kb + (size_t)b * Tn * Hn);

  // ================= phase 1: Q2 = (dagT@Q)/sqrt(H) =================
  f32x4 accq[4][2] = {};
  for (int kt = 0; kt < Tn; kt += 64) {
#pragma unroll
    for (int q = 0; q < 2; ++q) {          // dag tile 8KB
      int ch = wave * 2 + q;
      int flat = ch * 1024 + lane * 16;
      int row = flat >> 7, colb = flat & 127;
      int sw = (row & 7) << 4;
      gload16(Ab + (size_t)row * 1024 + kt * 2 + (colb ^ sw), smA + ch * 1024);
    }
#pragma unroll
    for (int q = 0; q < 4; ++q) {          // Q tile 16KB
      int ch = wave * 4 + q;
      int flat = ch * 1024 + lane * 16;
      int row = flat >> 7, colb = flat & 127;
      int sw = (row & 7) << 4;
      gload16(Qb + (size_t)row * 1024 + kt * 2 + (colb ^ sw), smA + 8192 + ch * 1024);
    }
    __syncthreads();
    bf16x8 af[4][2], fq[2][2];
#pragma unroll
    for (int m = 0; m < 4; ++m)
#pragma unroll
      for (int kk = 0; kk < 2; ++kk)
        af[m][kk] = *(const bf16x8*)(smA + (m * 16 + col0) * 128 + ((kk * 64 + g * 16) ^ swl));
#pragma unroll
    for (int n = 0; n < 2; ++n)
#pragma unroll
      for (int kk = 0; kk < 2; ++kk)
        fq[n][kk] = *(const bf16x8*)(smA + 8192 + (wave * 32 + n * 16 + col0) * 128 + ((kk * 64 + g * 16) ^ swl));
#pragma unroll
    for (int kk = 0; kk < 2; ++kk)
#pragma unroll
      for (int m = 0; m < 4; ++m)
#pragma unroll
        for (int n = 0; n < 2; ++n)
          accq[m][n] = __builtin_amdgcn_mfma_f32_16x16x32_bf16(af[m][kk], fq[n][kk], accq[m][n], 0, 0, 0);
    __syncthreads();
  }

  // Q2 -> LDS [q][h] (scaled); accq dies here
  const float scale = 0.08838834764831845f;
#pragma unroll
  for (int m = 0; m < 4; ++m)
#pragma unroll
    for (int n = 0; n < 2; ++n)
#pragma unroll
      for (int r = 0; r < 4; ++r) {
        int q = m * 16 + g * 4 + r;
        int h = wave * 32 + n * 16 + col0;
        *(u16*)((char*)smQ2 + q * 256 + ((h * 2) ^ ((q & 7) << 4))) = f2bf(accq[m][n][r] * scale);
      }

  // ================= phase 2: S^T = K Q2^T =================
#define STAGE_K(c_, buf_)                                                      \
  {                                                                            \
    _Pragma("unroll")                                                          \
    for (int q = 0; q < 8; ++q) {                                              \
      int ch = wave * 8 + q;                                                   \
      int flat = ch * 1024 + lane * 16;                                        \
      int row = flat >> 8, colb = flat & 255;                                  \
      gload16(Kb0 + (size_t)((c_) * 128 + row) * 256 + (colb ^ ((row & 7) << 4)), \
              smA + (buf_) * 32768 + ch * 1024);                               \
    }                                                                          \
  }

  STAGE_K(0, 0);
  __syncthreads();   // Q2 visible + K chunk 0 staged

  int qrow = wave * 16 + col0;
  bf16x8 bq[4];
#pragma unroll
  for (int kk = 0; kk < 4; ++kk)
    bq[kk] = *(const bf16x8*)((char*)smQ2 + qrow * 256 + ((kk * 64 + g * 16) ^ ((qrow & 7) << 4)));
  const u64* dbq = dbits + (size_t)(m0 + qrow) * 8;
  u64 md[8];
#pragma unroll
  for (int w = 0; w < 8; ++w) md[w] = dbq[w];

  f32x4 sa[32] = {};
#pragma unroll
  for (int c = 0; c < 4; ++c) {
    if (c < 3) STAGE_K(c + 1, (c + 1) & 1);
    const char* kb = smA + (c & 1) * 32768;
#pragma unroll
    for (int t = 0; t < 8; ++t)
#pragma unroll
      for (int kk = 0; kk < 4; ++kk) {
        bf16x8 ak = *(const bf16x8*)(kb + (t * 16 + col0) * 256 + ((kk * 64 + g * 16) ^ swl));
        sa[c * 8 + t] = __builtin_amdgcn_mfma_f32_16x16x32_bf16(ak, bq[kk], sa[c * 8 + t], 0, 0, 0);
      }
    if (c < 3) __syncthreads();
  }

  // ---- mask + max (lane-local + 2 shfl) ----
  float mx = -INFINITY;
#pragma unroll
  for (int t = 0; t < 32; ++t)
#pragma unroll
    for (int r = 0; r < 4; ++r) {
      int k = t * 16 + g * 4 + r;
      float v = ((md[k >> 6] >> (k & 63)) & 1) ? sa[t][r] : -INFINITY;
      sa[t][r] = v;
      mx = fmaxf(mx, v);
    }
  mx = fmaxf(mx, __shfl_xor(mx, 16, 64));
  mx = fmaxf(mx, __shfl_xor(mx, 32, 64));
  float mm = (mx == -INFINITY) ? 0.f : mx;

  // ---- exp in place, row sum (lane-local after 2 shfl) ----
  float s = 0.f;
#pragma unroll
  for (int t = 0; t < 32; ++t)
#pragma unroll
    for (int r = 0; r < 4; ++r) {
      float v = sa[t][r];
      float e = (v == -INFINITY) ? 0.f : __expf(v - mm);
      sa[t][r] = e;
      s += e;
    }
  s += __shfl_xor(s, 16, 64);
  s += __shfl_xor(s, 32, 64);
  float inv = (s > 0.f) ? (1.f / s) : 0.f;

  // ---- pack P' = e*inv + dagbit (dag@V folded into the P matmul) ----
  ushort4 pk[32];
#pragma unroll
  for (int t = 0; t < 32; ++t) {
    ushort4 p;
#pragma unroll
    for (int r = 0; r < 4; ++r) {
      int k = t * 16 + g * 4 + r;
      float d = (float)((md[k >> 6] >> (k & 63)) & 1);
      ((u16*)&p)[r] = f2bf(sa[t][r] * inv + d);
    }
    pk[t] = p;
  }

  // ================= phase 3: O = P'@V, P double-buffered =================
  // P bufs [0,16K) and [16K,32K) — both inside K-buf0, whose reads (chunk 2) are
  // fenced by the c=2 end-of-loop barrier; chunk-3 reads use [32K,64K). Safe.
  f32x4 acco[4][2] = {};
  int sww = (qrow & 7) << 4;

#define WRITE_P(c_, base_)                                                     \
  {                                                                            \
    _Pragma("unroll")                                                          \
    for (int tt = 0; tt < 8; ++tt)                                             \
      *(ushort4*)((base_) + qrow * 256 + ((tt * 32 + g * 8) ^ sww)) = pk[(c_) * 8 + tt]; \
  }

  WRITE_P(0, smA);
  __syncthreads();                         // P0 visible
#pragma unroll
  for (int c = 0; c < 4; ++c) {
    const char* pb = smA + (c & 1) * 16384;
    if (c < 3) WRITE_P(c + 1, smA + ((c + 1) & 1) * 16384);  // overlaps MFMA on P(c)
#pragma unroll
    for (int kk = 0; kk < 4; ++kk) {
      bf16x8 pa[4], vb[2];
#pragma unroll
      for (int m = 0; m < 4; ++m) {
        int row = m * 16 + col0;           // 64 q-rows
        pa[m] = *(const bf16x8*)(pb + row * 256 + ((kk * 64 + g * 16) ^ ((row & 7) << 4)));
      }
#pragma unroll
      for (int n = 0; n < 2; ++n)
        vb[n] = *(const bf16x8*)(Vb + (size_t)(wave * 32 + n * 16 + col0) * 1024 + c * 256 + kk * 64 + g * 16);
#pragma unroll
      for (int m = 0; m < 4; ++m)
#pragma unroll
        for (int n = 0; n < 2; ++n)
          acco[m][n] = __builtin_amdgcn_mfma_f32_16x16x32_bf16(pa[m], vb[n], acco[m][n], 0, 0, 0);
    }
    __syncthreads();                       // P(c+1) visible + P(c) reads done
  }

  // ---- epilogue: O = acco ----
#pragma unroll
  for (int m = 0; m < 4; ++m)
#pragma unroll
    for (int r = 0; r < 4; ++r) {
      int i = m0 + m * 16 + g * 4 + r;
#pragma unroll
      for (int n = 0; n < 2; ++n) {
        int h = wave * 32 + n * 16 + col0;
        O[((size_t)b * Tn + i) * Hn + h] = acco[m][n][r];
      }
    }
#undef STAGE_K
#undef WRITE_P
}

extern "C" void kernel_launch(void* const* d_in, const int* in_sizes, int n_in,
                              void* d_out, int out_size, void* d_ws, size_t ws_size,
                              hipStream_t stream) {
  const float* X   = (const float*)d_in[0];
  const float* dag = (const float*)d_in[1];
  const float* Wk  = (const float*)d_in[2];
  const float* bk  = (const float*)d_in[3];
  const float* Wq  = (const float*)d_in[4];
  const float* bq  = (const float*)d_in[5];
  const float* Wv  = (const float*)d_in[6];
  const float* bv  = (const float*)d_in[7];
  float* O = (float*)d_out;

  char* ws = (char*)d_ws;
  u16* Wcat = (u16*)(ws);                 //    393,216
  u16* dagT = (u16*)(ws + 393216);        //    524,288
  u64* dbits= (u64*)(ws + 917504);        //     32,768
  u16* Kb   = (u16*)(ws + 950272);        //  8,388,608
  u16* QT   = (u16*)(ws + 9338880);       //  8,388,608
  u16* VT   = (u16*)(ws + 17727488);      //  8,388,608  (end 26,116,096)

  prep<<<256, 256, 0, stream>>>((const float4*)Wk, (const float4*)Wq,
                                (const float4*)Wv, (ushort4*)Wcat, dag, dagT, dbits);
  qkv3<<<BT / 64, 256, 0, stream>>>(X, Wcat, bk, bq, bv, Kb, QT, VT);
  dattn<<<512, 256, 0, stream>>>(dagT, QT, VT, Kb, dbits, O);
}

// Round 17
// 64.374 us; speedup vs baseline: 1.2369x; 1.0227x over previous
//
#include <hip/hip_runtime.h>
#include <hip/hip_bf16.h>

#define Bn 64
#define Tn 512
#define Dn 512
#define Hn 128
#define BT (Bn*Tn)

typedef unsigned short u16;
typedef unsigned long long u64;
typedef __attribute__((ext_vector_type(8))) short bf16x8;
typedef __attribute__((ext_vector_type(4))) float f32x4;

__device__ __forceinline__ u16 f2bf(float f) {
  union { float f; unsigned u; } v; v.f = f;
  unsigned r = (v.u + 0x7FFFu + ((v.u >> 16) & 1u)) >> 16;
  return (u16)r;
}

__device__ __forceinline__ bf16x8 pack8(float4 a, float4 b) {
  bf16x8 o;
  o[0] = (short)f2bf(a.x); o[1] = (short)f2bf(a.y);
  o[2] = (short)f2bf(a.z); o[3] = (short)f2bf(a.w);
  o[4] = (short)f2bf(b.x); o[5] = (short)f2bf(b.y);
  o[6] = (short)f2bf(b.z); o[7] = (short)f2bf(b.w);
  return o;
}

// async global->LDS, 16B/lane; LDS dest = wave-uniform base (+lane*16 by HW)
__device__ __forceinline__ void gload16(const void* g, void* lds) {
  __builtin_amdgcn_global_load_lds(
      (const __attribute__((address_space(1))) unsigned int*)g,
      (__attribute__((address_space(3))) unsigned int*)lds, 16, 0, 0);
}

// ---------- prep (merged): blocks 0..191 = W->bf16; blocks 192..255 = dag transpose+bits ----------
__global__ __launch_bounds__(256) void prep(
    const float4* __restrict__ Wk, const float4* __restrict__ Wq,
    const float4* __restrict__ Wv, ushort4* __restrict__ Wcat,
    const float* __restrict__ dag, u16* __restrict__ dagT,
    u64* __restrict__ bits) {
  __shared__ float s[64][65];
  if (blockIdx.x < 192) {
    int idx = blockIdx.x * 256 + threadIdx.x;        // 3 * 16384
    int which = idx >> 14, j = idx & 16383;
    const float4* src = (which == 0) ? Wk : (which == 1) ? Wq : Wv;
    float4 v = src[j];
    ushort4 o; o.x = f2bf(v.x); o.y = f2bf(v.y); o.z = f2bf(v.z); o.w = f2bf(v.w);
    Wcat[idx] = o;
  } else {
    int bid = blockIdx.x - 192;                      // 0..63
    int bx = bid & 7, by = bid >> 3;
    int r0 = by * 64, c0 = bx * 64;
    int t = threadIdx.x;
    int c4 = t & 15, rr = t >> 4;
#pragma unroll
    for (int q = 0; q < 4; ++q) {
      int r = rr + q * 16;
      float4 v = *(const float4*)&dag[(size_t)(r0 + r) * Tn + c0 + c4 * 4];
      s[c4 * 4 + 0][r] = v.x; s[c4 * 4 + 1][r] = v.y;
      s[c4 * 4 + 2][r] = v.z; s[c4 * 4 + 3][r] = v.w;
    }
    __syncthreads();
#pragma unroll
    for (int q = 0; q < 4; ++q) {
      int il = rr + q * 16;
      ushort4 o;
      u64 b4 = 0;
#pragma unroll
      for (int r = 0; r < 4; ++r) {
        float v = s[il][c4 * 4 + r];
        ((u16*)&o)[r] = f2bf(v);
        b4 |= (u64)(v != 0.f) << (c4 * 4 + r);
      }
      *(ushort4*)&dagT[(size_t)(c0 + il) * Tn + r0 + c4 * 4] = o;
      b4 |= __shfl_xor(b4, 1, 64);
      b4 |= __shfl_xor(b4, 2, 64);
      b4 |= __shfl_xor(b4, 4, 64);
      b4 |= __shfl_xor(b4, 8, 64);
      if (c4 == 0) bits[(size_t)(c0 + il) * 8 + (r0 >> 6)] = b4;
    }
  }
}

// ---------- stage 1: K,Q,V = swish(X W^T + b); BM=64, 512 threads (8 waves), 4 waves/SIMD ----------
// grid 512 (XCD-swizzled by b). Wave w owns h-cols w*16..w*16+15 of all 3 outputs.
__global__ __launch_bounds__(512, 4) void qkv3(
    const float* __restrict__ X, const u16* __restrict__ Wcat,
    const float* __restrict__ bk, const float* __restrict__ bq,
    const float* __restrict__ bv,
    u16* __restrict__ Kb, u16* __restrict__ QT, u16* __restrict__ VT) {
  __shared__ u16 sm[28672];   // 56KB: X(8KB) | Wk|Wq|Wv (16KB each); epilogue bounce 48KB
  int bid = blockIdx.x;
  int xcd = bid & 7, idx = bid >> 3;       // idx 0..63
  int b = (idx & 7) * 8 + xcd;             // 0..63
  int rowblk = idx >> 3;                   // 0..7
  int m0 = b * Tn + rowblk * 64;           // global token row
  int tid = threadIdx.x, lane = tid & 63, wave = tid >> 6;   // 8 waves
  int col0 = lane & 15, rg = lane >> 4, kcb = rg * 16;
  int swl = (col0 & 7) << 4;
  int xrow = tid >> 3, xc8 = tid & 7;      // X staging: row (0..63), 8-float chunk
  f32x4 acc[3][4] = {};                    // [which][m], wave's single 16-col n
  const char* Wb = (const char*)Wcat;
  char* smb = (char*)sm;

#define LOAD_X(kt_)                                                             \
  {                                                                             \
    const float4* s_ = (const float4*)(X + (size_t)(m0 + xrow) * Dn + (kt_) + xc8 * 8); \
    xa0 = s_[0]; xa1 = s_[1];                                                   \
  }

  float4 xa0, xa1;
  LOAD_X(0);
  for (int kt = 0; kt < Dn; kt += 64) {
    // pack current X regs -> LDS (prev MFMA reads fenced by loop-tail sync)
    {
      int sw = (xrow & 7) << 4;
      *(bf16x8*)(smb + xrow * 128 + ((xc8 * 16) ^ sw)) = pack8(xa0, xa1);
    }
    if (kt + 64 < Dn) LOAD_X(kt + 64);     // T14 prefetch
    // W: 48KB via gload16, pre-swizzled source (6 issues/thread)
#pragma unroll
    for (int q = 0; q < 6; ++q) {
      int c2 = wave * 6 + q;               // 0..47
      int which = c2 >> 4, widx = c2 & 15;
      int flat = widx * 1024 + lane * 16;
      int row = flat >> 7, colb = flat & 127;
      int sw = (row & 7) << 4;
      gload16(Wb + (size_t)which * 131072 + (size_t)row * 1024 + (kt << 1) + (colb ^ sw),
              smb + 8192 + which * 16384 + widx * 1024);
    }
    __syncthreads();
    bf16x8 af[4][2];
#pragma unroll
    for (int m = 0; m < 4; ++m)
#pragma unroll
      for (int kk = 0; kk < 2; ++kk)
        af[m][kk] = *(const bf16x8*)(smb + (m * 16 + col0) * 128 + ((kk * 64 + kcb) ^ swl));
#pragma unroll
    for (int which = 0; which < 3; ++which) {
      bf16x8 bfr[2];
#pragma unroll
      for (int kk = 0; kk < 2; ++kk)
        bfr[kk] = *(const bf16x8*)(smb + 8192 + which * 16384 +
                                   (wave * 16 + col0) * 128 + ((kk * 64 + kcb) ^ swl));
#pragma unroll
      for (int kk = 0; kk < 2; ++kk)
#pragma unroll
        for (int m = 0; m < 4; ++m)
          acc[which][m] = __builtin_amdgcn_mfma_f32_16x16x32_bf16(
              af[m][kk], bfr[kk], acc[which][m], 0, 0, 0);
    }
    __syncthreads();
  }
#undef LOAD_X

  // ---- epilogue: K/Q/V to disjoint LDS regions, ONE sync, full-line stores ----
  // K [0,16K) layout [t][h] 256B rows; Q [16K,32K), V [32K,48K) layout [h][t] 128B rows.
  {
    int nl = wave * 16 + col0;
    float bsk = bk[nl], bsq = bq[nl], bsv = bv[nl];
#pragma unroll
    for (int m = 0; m < 4; ++m)
#pragma unroll
      for (int r = 0; r < 4; ++r) {
        int tl = m * 16 + rg * 4 + r;      // 0..63
        float xk = acc[0][m][r] + bsk;
        float xq = acc[1][m][r] + bsq;
        float xv = acc[2][m][r] + bsv;
        *(u16*)(smb + tl * 256 + ((nl * 2) ^ ((tl & 7) << 4))) = f2bf(xk / (1.f + __expf(-xk)));
        *(u16*)(smb + 16384 + nl * 128 + ((tl * 2) ^ ((nl & 7) << 4))) = f2bf(xq / (1.f + __expf(-xq)));
        *(u16*)(smb + 32768 + nl * 128 + ((tl * 2) ^ ((nl & 7) << 4))) = f2bf(xv / (1.f + __expf(-xv)));
      }
    __syncthreads();
    int tt0 = rowblk * 64;
#pragma unroll
    for (int p = 0; p < 2; ++p) {
      int c = p * 512 + tid;               // 1024 x 16B
      int t = c >> 4, c16 = c & 15;
      *(bf16x8*)&Kb[(size_t)(m0 + t) * Hn + c16 * 8] =
          *(const bf16x8*)(smb + t * 256 + ((c16 * 16) ^ ((t & 7) << 4)));
    }
#pragma unroll
    for (int p = 0; p < 2; ++p) {
      int c = p * 512 + tid;               // 1024 x 16B
      int h = c >> 3, c8 = c & 7;
      *(bf16x8*)&QT[((size_t)b * Hn + h) * Tn + tt0 + c8 * 8] =
          *(const bf16x8*)(smb + 16384 + h * 128 + ((c8 * 16) ^ ((h & 7) << 4)));
      *(bf16x8*)&VT[((size_t)b * Hn + h) * Tn + tt0 + c8 * 8] =
          *(const bf16x8*)(smb + 32768 + h * 128 + ((c8 * 16) ^ ((h & 7) << 4)));
    }
  }
}

// ---------- stage 2+3+4 fused, 512 threads (8 waves), 4 waves/SIMD ----------
// grid 512 (XCD-swizzled). Phase 1: Q2=(dagT@Q)/sqrt(H)->LDS; wave w owns h-cols w*16..
// Phase 2: S^T = K Q2^T; wave-group grp=wave>>2: grp 0 keys 0..255, grp 1 keys 256..511;
//   each group dbufs 64-key K chunks in its own 32KB region; two-stage softmax via 1KB LDS.
// Phase 3: O = P'@V (P' = e/s + dagbit); P chunks written by owning group, read by all.
__global__ __launch_bounds__(512, 4) void dattn(
    const u16* __restrict__ dagT, const u16* __restrict__ QT,
    const u16* __restrict__ VT, const u16* __restrict__ Kb,
    const u64* __restrict__ dbits, float* __restrict__ O) {
  __shared__ char smA[65536];   // ph1: dag[0,8K)|Q[8K,24K); ph2: K grp0 2x16K @0, grp1 2x16K @32K; ph3: P dbuf 2x16K
  __shared__ u16 smQ2[8192];    // 16KB Q2 [q][h]; reused (1KB) for softmax combine

  int bid = blockIdx.x;
  int xcd = bid & 7, rst = bid >> 3;       // rst 0..63
  int bx = rst & 7, b = (rst >> 3) * 8 + xcd;
  int m0 = bx * 64;
  int tid = threadIdx.x, lane = tid & 63, wave = tid >> 6;   // 8 waves
  int col0 = lane & 15, g = lane >> 4;
  int swl = (col0 & 7) << 4;
  int grp = wave >> 2, gw = wave & 3;

  const char* Ab = (const char*)(dagT + (size_t)m0 * Tn);
  const char* Qb = (const char*)(QT + (size_t)b * Hn * Tn);
  const char* Vb = (const char*)(VT + (size_t)b * Hn * Tn);
  const char* Kb0 = (const char*)(Kb + (size_t)b * Tn * Hn);

  // ================= phase 1: Q2 = (dagT@Q)/sqrt(H) =================
  f32x4 accq[4] = {};
  for (int kt = 0; kt < Tn; kt += 64) {
    {                                      // dag tile 8KB: 1 issue/thread
      int ch = wave;
      int flat = ch * 1024 + lane * 16;
      int row = flat >> 7, colb = flat & 127;
      int sw = (row & 7) << 4;
      gload16(Ab + (size_t)row * 1024 + kt * 2 + (colb ^ sw), smA + ch * 1024);
    }
#pragma unroll
    for (int q = 0; q < 2; ++q) {          // Q tile 16KB: 2 issues/thread
      int ch = wave * 2 + q;
      int flat = ch * 1024 + lane * 16;
      int row = flat >> 7, colb = flat & 127;
      int sw = (row & 7) << 4;
      gload16(Qb + (size_t)row * 1024 + kt * 2 + (colb ^ sw), smA + 8192 + ch * 1024);
    }
    __syncthreads();
    bf16x8 af[4][2], fq[2];
#pragma unroll
    for (int m = 0; m < 4; ++m)
#pragma unroll
      for (int kk = 0; kk < 2; ++kk)
        af[m][kk] = *(const bf16x8*)(smA + (m * 16 + col0) * 128 + ((kk * 64 + g * 16) ^ swl));
#pragma unroll
    for (int kk = 0; kk < 2; ++kk)
      fq[kk] = *(const bf16x8*)(smA + 8192 + (wave * 16 + col0) * 128 + ((kk * 64 + g * 16) ^ swl));
#pragma unroll
    for (int kk = 0; kk < 2; ++kk)
#pragma unroll
      for (int m = 0; m < 4; ++m)
        accq[m] = __builtin_amdgcn_mfma_f32_16x16x32_bf16(af[m][kk], fq[kk], accq[m], 0, 0, 0);
    __syncthreads();
  }

  // Q2 -> LDS [q][h] (scaled); accq dies here
  const float scale = 0.08838834764831845f;
#pragma unroll
  for (int m = 0; m < 4; ++m)
#pragma unroll
    for (int r = 0; r < 4; ++r) {
      int q = m * 16 + g * 4 + r;
      int h = wave * 16 + col0;
      *(u16*)((char*)smQ2 + q * 256 + ((h * 2) ^ ((q & 7) << 4))) = f2bf(accq[m][r] * scale);
    }

  // ================= phase 2: S^T = K Q2^T, key-split across wave groups =================
  // group grp stages 64-key chunks into smA[grp*32K + (c&1)*16K, +16K)
#define STAGE_K(c_)                                                            \
  {                                                                            \
    _Pragma("unroll")                                                          \
    for (int q = 0; q < 4; ++q) {                                              \
      int ch = gw * 4 + q;                                                     \
      int flat = ch * 1024 + lane * 16;                                        \
      int row = flat >> 8, colb = flat & 255;                                  \
      gload16(Kb0 + (size_t)(grp * 256 + (c_) * 64 + row) * 256 + (colb ^ ((row & 7) << 4)), \
              smA + grp * 32768 + ((c_) & 1) * 16384 + ch * 1024);             \
    }                                                                          \
  }

  STAGE_K(0);
  __syncthreads();   // Q2 visible + first chunks staged

  int qrow = gw * 16 + col0;               // this wave's query (block-local)
  bf16x8 bq[4];
#pragma unroll
  for (int kk = 0; kk < 4; ++kk)
    bq[kk] = *(const bf16x8*)((char*)smQ2 + qrow * 256 + ((kk * 64 + g * 16) ^ ((qrow & 7) << 4)));
  const u64* dbq = dbits + (size_t)(m0 + qrow) * 8;
  u64 md[4];
#pragma unroll
  for (int w = 0; w < 4; ++w) md[w] = dbq[grp * 4 + w];

  f32x4 sa[16] = {};
#pragma unroll
  for (int c = 0; c < 4; ++c) {
    if (c < 3) STAGE_K(c + 1);
    const char* kb = smA + grp * 32768 + (c & 1) * 16384;
#pragma unroll
    for (int t = 0; t < 4; ++t)
#pragma unroll
      for (int kk = 0; kk < 4; ++kk) {
        bf16x8 ak = *(const bf16x8*)(kb + (t * 16 + col0) * 256 + ((kk * 64 + g * 16) ^ swl));
        sa[c * 4 + t] = __builtin_amdgcn_mfma_f32_16x16x32_bf16(ak, bq[kk], sa[c * 4 + t], 0, 0, 0);
      }
    if (c < 3) __syncthreads();
  }

  // ---- mask + group-local max (lane-local + 2 shfl) ----
  float mx = -INFINITY;
#pragma unroll
  for (int c = 0; c < 4; ++c)
#pragma unroll
    for (int t = 0; t < 4; ++t)
#pragma unroll
      for (int r = 0; r < 4; ++r) {
        int bit = t * 16 + g * 4 + r;
        float v = ((md[c] >> bit) & 1) ? sa[c * 4 + t][r] : -INFINITY;
        sa[c * 4 + t][r] = v;
        mx = fmaxf(mx, v);
      }
  mx = fmaxf(mx, __shfl_xor(mx, 16, 64));
  mx = fmaxf(mx, __shfl_xor(mx, 32, 64));

  // ---- cross-group combine via LDS (smQ2 reused; bq reads fenced by S-loop barriers) ----
  float* redf = (float*)smQ2;              // [0,128): max; [128,256): sum
  __syncthreads();                         // all S MFMA / staging done; safe to overwrite smQ2? (bq read pre-loop)
  if (g == 0) redf[qrow * 2 + grp] = mx;
  __syncthreads();
  float mboth = fmaxf(redf[qrow * 2], redf[qrow * 2 + 1]);
  float mm = (mboth == -INFINITY) ? 0.f : mboth;

  float s = 0.f;
#pragma unroll
  for (int i = 0; i < 16; ++i)
#pragma unroll
    for (int r = 0; r < 4; ++r) {
      float v = sa[i][r];
      float e = (v == -INFINITY) ? 0.f : __expf(v - mm);
      sa[i][r] = e;
      s += e;
    }
  s += __shfl_xor(s, 16, 64);
  s += __shfl_xor(s, 32, 64);
  if (g == 0) redf[128 + qrow * 2 + grp] = s;
  __syncthreads();
  float stot = redf[128 + qrow * 2] + redf[128 + qrow * 2 + 1];
  float inv = (stot > 0.f) ? (1.f / stot) : 0.f;

  // ---- pack P' = e*inv + dagbit ----
  ushort4 pk[16];
#pragma unroll
  for (int c = 0; c < 4; ++c)
#pragma unroll
    for (int t = 0; t < 4; ++t) {
      ushort4 p;
#pragma unroll
      for (int r = 0; r < 4; ++r) {
        int bit = t * 16 + g * 4 + r;
        float d = (float)((md[c] >> bit) & 1);
        ((u16*)&p)[r] = f2bf(sa[c * 4 + t][r] * inv + d);
      }
      pk[c * 4 + t] = p;
    }

  // ================= phase 3: O = P'@V, P double-buffered in smA[0,32K) =================
  f32x4 acco[4] = {};
  int sww = (qrow & 7) << 4;

  // WRITE_P(c): only group (c>>1) writes chunk c (128 keys); cc = c&1 selects its half.
#define WRITE_P(c_, base_)                                                     \
  if (grp == ((c_) >> 1)) {                                                    \
    int cc = (c_) & 1;                                                         \
    _Pragma("unroll")                                                          \
    for (int u = 0; u < 2; ++u)                                                \
      _Pragma("unroll")                                                        \
      for (int t2 = 0; t2 < 4; ++t2)                                           \
        *(ushort4*)((base_) + qrow * 256 + ((u * 128 + t2 * 32 + g * 8) ^ sww)) = \
            pk[(cc * 2 + u) * 4 + t2];                                         \
  }

  __syncthreads();                         // all sa-phase LDS reads done (K bufs dead)
  WRITE_P(0, smA);
  __syncthreads();                         // P0 visible
#pragma unroll
  for (int c = 0; c < 4; ++c) {
    const char* pb = smA + (c & 1) * 16384;
    if (c < 3) WRITE_P(c + 1, smA + ((c + 1) & 1) * 16384);   // overlaps MFMA on P(c)
#pragma unroll
    for (int kk = 0; kk < 4; ++kk) {
      bf16x8 pa[4], vb;
#pragma unroll
      for (int m = 0; m < 4; ++m) {
        int row = m * 16 + col0;           // 64 q-rows
        pa[m] = *(const bf16x8*)(pb + row * 256 + ((kk * 64 + g * 16) ^ ((row & 7) << 4)));
      }
      vb = *(const bf16x8*)(Vb + (size_t)(wave * 16 + col0) * 1024 + c * 256 + kk * 64 + g * 16);
#pragma unroll
      for (int m = 0; m < 4; ++m)
        acco[m] = __builtin_amdgcn_mfma_f32_16x16x32_bf16(pa[m], vb, acco[m], 0, 0, 0);
    }
    __syncthreads();                       // P(c+1) visible + P(c) reads done
  }

  // ---- epilogue: O = acco ----
#pragma unroll
  for (int m = 0; m < 4; ++m)
#pragma unroll
    for (int r = 0; r < 4; ++r) {
      int i = m0 + m * 16 + g * 4 + r;
      int h = wave * 16 + col0;
      O[((size_t)b * Tn + i) * Hn + h] = acco[m][r];
    }
#undef STAGE_K
#undef WRITE_P
}

extern "C" void kernel_launch(void* const* d_in, const int* in_sizes, int n_in,
                              void* d_out, int out_size, void* d_ws, size_t ws_size,
                              hipStream_t stream) {
  const float* X   = (const float*)d_in[0];
  const float* dag = (const float*)d_in[1];
  const float* Wk  = (const float*)d_in[2];
  const float* bk  = (const float*)d_in[3];
  const float* Wq  = (const float*)d_in[4];
  const float* bq  = (const float*)d_in[5];
  const float* Wv  = (const float*)d_in[6];
  const float* bv  = (const float*)d_in[7];
  float* O = (float*)d_out;

  char* ws = (char*)d_ws;
  u16* Wcat = (u16*)(ws);                 //    393,216
  u16* dagT = (u16*)(ws + 393216);        //    524,288
  u64* dbits= (u64*)(ws + 917504);        //     32,768
  u16* Kb   = (u16*)(ws + 950272);        //  8,388,608
  u16* QT   = (u16*)(ws + 9338880);       //  8,388,608
  u16* VT   = (u16*)(ws + 17727488);      //  8,388,608  (end 26,116,096)

  prep<<<256, 256, 0, stream>>>((const float4*)Wk, (const float4*)Wq,
                                (const float4*)Wv, (ushort4*)Wcat, dag, dagT, dbits);
  qkv3<<<BT / 64, 512, 0, stream>>>(X, Wcat, bk, bq, bv, Kb, QT, VT);
  dattn<<<512, 512, 0, stream>>>(dagT, QT, VT, Kb, dbits, O);
}